// Round 1
// baseline (80.887 us; speedup 1.0000x reference)
//
#include <hip/hip_runtime.h>

// CategorySpecificLinear: out[t] = x[t] @ W[cid[t]] + bias[cid[t]]
// T=B*S tokens, D in-features, O out-features, C categories.
// Pipeline: memset counts -> cvt x->bf16 -> transpose W->Wt bf16 -> bucketize -> grouped MFMA GEMM.

typedef __attribute__((ext_vector_type(8))) short bf16x8;
typedef __attribute__((ext_vector_type(4))) float f32x4;
typedef __attribute__((ext_vector_type(8))) unsigned short ushort8_t;

__device__ __forceinline__ unsigned short f2bf(float f) {
  unsigned u = __float_as_uint(f);
  u += 0x7FFFu + ((u >> 16) & 1u);   // round-to-nearest-even
  return (unsigned short)(u >> 16);
}

// ---- kernel 1: x fp32 -> bf16 (vectorized 8/thread) ----
__global__ void k_cvt_x(const float* __restrict__ x, unsigned short* __restrict__ xb, int n) {
  int i = (blockIdx.x * blockDim.x + threadIdx.x) * 8;
  if (i >= n) return;
  float4 a = *reinterpret_cast<const float4*>(x + i);
  float4 b = *reinterpret_cast<const float4*>(x + i + 4);
  ushort8_t o;
  o[0] = f2bf(a.x); o[1] = f2bf(a.y); o[2] = f2bf(a.z); o[3] = f2bf(a.w);
  o[4] = f2bf(b.x); o[5] = f2bf(b.y); o[6] = f2bf(b.z); o[7] = f2bf(b.w);
  *reinterpret_cast<ushort8_t*>(xb + i) = o;
}

// ---- kernel 2: W[c][d][o] fp32 -> Wt[c][o][d] bf16 (64x64 LDS tiles) ----
__global__ void k_transpose_w(const float* __restrict__ W, unsigned short* __restrict__ Wt,
                              int Dd, int Oo) {
  __shared__ float t[64][65];  // +1 pad breaks bank conflicts on column reads
  int c = blockIdx.z, d0 = blockIdx.y * 64, o0 = blockIdx.x * 64;
  const float* Wc = W + (size_t)c * Dd * Oo;
  int tid = threadIdx.x;
#pragma unroll
  for (int p = 0; p < 4; ++p) {
    int chunk = p * 256 + tid;
    int r  = chunk >> 4;    // d row 0..63
    int cb = chunk & 15;    // o col block
    float4 v = *reinterpret_cast<const float4*>(Wc + (size_t)(d0 + r) * Oo + o0 + cb * 4);
    t[r][cb * 4 + 0] = v.x; t[r][cb * 4 + 1] = v.y;
    t[r][cb * 4 + 2] = v.z; t[r][cb * 4 + 3] = v.w;
  }
  __syncthreads();
  unsigned short* Wtc = Wt + (size_t)c * Oo * Dd;
#pragma unroll
  for (int p = 0; p < 4; ++p) {
    int chunk = p * 256 + tid;
    int orow = chunk >> 4;  // o row 0..63
    int db   = chunk & 15;  // d block
    ushort4 w;
    w.x = f2bf(t[db * 4 + 0][orow]); w.y = f2bf(t[db * 4 + 1][orow]);
    w.z = f2bf(t[db * 4 + 2][orow]); w.w = f2bf(t[db * 4 + 3][orow]);
    *reinterpret_cast<ushort4*>(Wtc + (size_t)(o0 + orow) * Dd + d0 + db * 4) = w;
  }
}

// ---- kernel 3: bucketize tokens by category ----
__global__ void k_bucketize(const int* __restrict__ cid, int* __restrict__ counts,
                            int* __restrict__ bucket, int T) {
  int t = blockIdx.x * blockDim.x + threadIdx.x;
  if (t >= T) return;
  int c = cid[t];
  int p = atomicAdd(&counts[c], 1);
  bucket[c * T + p] = t;
}

// ---- kernel 4: grouped GEMM, gather rows per category ----
#define BM 128
#define BN 128
#define BK 32

__global__ __launch_bounds__(256) void k_ggemm(
    const unsigned short* __restrict__ xb, const unsigned short* __restrict__ Wt,
    const float* __restrict__ bias, const int* __restrict__ counts,
    const int* __restrict__ bucket, float* __restrict__ out,
    int T, int Dd, int Oo) {
  int c  = blockIdx.z;
  int Mc = counts[c];
  int m0 = blockIdx.y * BM;
  if (m0 >= Mc) return;  // block-uniform exit
  int n0 = blockIdx.x * BN;

  __shared__ __align__(16) unsigned short Al[BM * BK];  // 8KB, 16B-slot swizzled
  __shared__ __align__(16) unsigned short Bl[BN * BK];  // 8KB

  const int tid  = threadIdx.x;
  const int lane = tid & 63;
  const int wid  = tid >> 6;
  const int wm   = wid >> 1, wn = wid & 1;  // 2x2 waves, 64x64 each

  const int* buck = bucket + c * T;
  int row0 = tid >> 2;   // 0..63 (this thread stages rows row0 and row0+64)
  int seg  = tid & 3;    // which 16B (8-bf16) chunk of the 32-wide k-slab

  int mr0 = m0 + row0, mr1 = m0 + 64 + row0;
  int tok0 = buck[mr0 < Mc ? mr0 : Mc - 1];  // clamp: masked at epilogue
  int tok1 = buck[mr1 < Mc ? mr1 : Mc - 1];

  const unsigned short* pA0 = xb + (size_t)tok0 * Dd + seg * 8;
  const unsigned short* pA1 = xb + (size_t)tok1 * Dd + seg * 8;
  const unsigned short* Wc  = Wt + (size_t)c * Oo * Dd;
  const unsigned short* pB0 = Wc + (size_t)(n0 + row0) * Dd + seg * 8;
  const unsigned short* pB1 = Wc + (size_t)(n0 + 64 + row0) * Dd + seg * 8;

  // swizzle: 16B slot index ^= (row>>1)&3 ; note swz(row)==swz(row+64)
  int sw = (row0 >> 1) & 3;
  int wa = row0 * BK + ((seg ^ sw) * 8);

  const f32x4 fzero = {0.f, 0.f, 0.f, 0.f};
  f32x4 acc[4][4];
  for (int i = 0; i < 4; ++i)
    for (int j = 0; j < 4; ++j) acc[i][j] = fzero;

  const int KT = Dd / BK;
  for (int kt = 0; kt < KT; ++kt) {
    uint4 va0 = *reinterpret_cast<const uint4*>(pA0);
    uint4 va1 = *reinterpret_cast<const uint4*>(pA1);
    uint4 vb0 = *reinterpret_cast<const uint4*>(pB0);
    uint4 vb1 = *reinterpret_cast<const uint4*>(pB1);
    pA0 += BK; pA1 += BK; pB0 += BK; pB1 += BK;
    __syncthreads();  // previous iter's LDS reads done
    *reinterpret_cast<uint4*>(&Al[wa])           = va0;
    *reinterpret_cast<uint4*>(&Al[wa + 64 * BK]) = va1;
    *reinterpret_cast<uint4*>(&Bl[wa])           = vb0;
    *reinterpret_cast<uint4*>(&Bl[wa + 64 * BK]) = vb1;
    __syncthreads();

    bf16x8 af[4], bfr[4];
#pragma unroll
    for (int mi = 0; mi < 4; ++mi) {
      int row  = wm * 64 + mi * 16 + (lane & 15);
      int g    = lane >> 4;
      int slot = g ^ ((row >> 1) & 3);
      af[mi] = *reinterpret_cast<const bf16x8*>(&Al[row * BK + slot * 8]);
    }
#pragma unroll
    for (int ni = 0; ni < 4; ++ni) {
      int row  = wn * 64 + ni * 16 + (lane & 15);
      int g    = lane >> 4;
      int slot = g ^ ((row >> 1) & 3);
      bfr[ni] = *reinterpret_cast<const bf16x8*>(&Bl[row * BK + slot * 8]);
    }
#pragma unroll
    for (int mi = 0; mi < 4; ++mi)
#pragma unroll
      for (int ni = 0; ni < 4; ++ni)
        acc[mi][ni] = __builtin_amdgcn_mfma_f32_16x16x32_bf16(af[mi], bfr[ni], acc[mi][ni], 0, 0, 0);
  }

  // epilogue: D layout col=lane&15, row=(lane>>4)*4+r  [m89-verified]
#pragma unroll
  for (int mi = 0; mi < 4; ++mi) {
    int rb = m0 + wm * 64 + mi * 16 + (lane >> 4) * 4;
#pragma unroll
    for (int r = 0; r < 4; ++r) {
      int mrow = rb + r;
      if (mrow < Mc) {
        int tok = buck[mrow];
        float* orow = out + (size_t)tok * Oo;
#pragma unroll
        for (int ni = 0; ni < 4; ++ni) {
          int col = n0 + wn * 64 + ni * 16 + (lane & 15);
          orow[col] = acc[mi][ni][r] + bias[c * Oo + col];
        }
      }
    }
  }
}

extern "C" void kernel_launch(void* const* d_in, const int* in_sizes, int n_in,
                              void* d_out, int out_size, void* d_ws, size_t ws_size,
                              hipStream_t stream) {
  const float* x    = (const float*)d_in[0];
  const int*   cid  = (const int*)d_in[1];
  const float* W    = (const float*)d_in[2];
  const float* bias = (const float*)d_in[3];
  float* out = (float*)d_out;

  int T = in_sizes[1];            // 4096
  int D = in_sizes[0] / T;        // 1024
  int O = out_size / T;           // 1024
  int C = in_sizes[3] / O;        // 8

  char* ws = (char*)d_ws;
  int* counts = (int*)ws;                                   // C ints
  int* bucket = (int*)(ws + 64);                            // C*T ints
  unsigned short* xb = (unsigned short*)(ws + 64 + (size_t)C * T * 4);   // T*D bf16
  unsigned short* Wt = xb + (size_t)T * D;                  // C*O*D bf16

  hipMemsetAsync(counts, 0, C * sizeof(int), stream);
  k_cvt_x<<<(T * D / 8 + 255) / 256, 256, 0, stream>>>(x, xb, T * D);
  k_transpose_w<<<dim3(O / 64, D / 64, C), 256, 0, stream>>>(W, Wt, D, O);
  k_bucketize<<<(T + 255) / 256, 256, 0, stream>>>(cid, counts, bucket, T);
  k_ggemm<<<dim3(O / BN, (T + BM - 1) / BM, C), 256, 0, stream>>>(
      xb, Wt, bias, counts, bucket, out, T, D, O);
}

// Round 2
// 72.215 us; speedup vs baseline: 1.1201x; 1.1201x over previous
//
#include <hip/hip_runtime.h>

// CategorySpecificLinear: out[t] = x[t] @ W[cid[t]] + bias[cid[t]]
// Pipeline: memset counts -> cvt x->bf16 -> transpose W->Wt bf16 -> bucketize
//           -> grouped MFMA GEMM (2-phase double-buffered, global_load_lds).

typedef __attribute__((ext_vector_type(8))) short bf16x8;
typedef __attribute__((ext_vector_type(4))) float f32x4;
typedef __attribute__((ext_vector_type(8))) unsigned short ushort8_t;

__device__ __forceinline__ unsigned short f2bf(float f) {
  unsigned u = __float_as_uint(f);
  u += 0x7FFFu + ((u >> 16) & 1u);   // round-to-nearest-even
  return (unsigned short)(u >> 16);
}

// async global->LDS, 16B per lane; LDS dest is wave-uniform base + lane*16
__device__ __forceinline__ void gload_lds16(const unsigned short* g, unsigned short* l) {
  __builtin_amdgcn_global_load_lds(
      (const __attribute__((address_space(1))) unsigned int*)g,
      (__attribute__((address_space(3))) unsigned int*)l, 16, 0, 0);
}

// ---- kernel 1: x fp32 -> bf16 (8/thread) ----
__global__ void k_cvt_x(const float* __restrict__ x, unsigned short* __restrict__ xb, int n) {
  int i = (blockIdx.x * blockDim.x + threadIdx.x) * 8;
  if (i >= n) return;
  float4 a = *reinterpret_cast<const float4*>(x + i);
  float4 b = *reinterpret_cast<const float4*>(x + i + 4);
  ushort8_t o;
  o[0] = f2bf(a.x); o[1] = f2bf(a.y); o[2] = f2bf(a.z); o[3] = f2bf(a.w);
  o[4] = f2bf(b.x); o[5] = f2bf(b.y); o[6] = f2bf(b.z); o[7] = f2bf(b.w);
  *reinterpret_cast<ushort8_t*>(xb + i) = o;
}

// ---- kernel 2: W[c][d][o] fp32 -> Wt[c][o][d] bf16, 64x64 tiles, 16B writes ----
__global__ void k_transpose_w(const float* __restrict__ W, unsigned short* __restrict__ Wt,
                              int Dd, int Oo) {
  __shared__ float t[64][65];
  int c = blockIdx.z, d0 = blockIdx.y * 64, o0 = blockIdx.x * 64;
  const float* Wc = W + (size_t)c * Dd * Oo;
  int tid = threadIdx.x;
#pragma unroll
  for (int p = 0; p < 4; ++p) {
    int chunk = p * 256 + tid;
    int r  = chunk >> 4;    // d row 0..63
    int cb = chunk & 15;    // o col block
    float4 v = *reinterpret_cast<const float4*>(Wc + (size_t)(d0 + r) * Oo + o0 + cb * 4);
    t[r][cb * 4 + 0] = v.x; t[r][cb * 4 + 1] = v.y;
    t[r][cb * 4 + 2] = v.z; t[r][cb * 4 + 3] = v.w;
  }
  __syncthreads();
  unsigned short* Wtc = Wt + (size_t)c * Oo * Dd;
#pragma unroll
  for (int p = 0; p < 2; ++p) {
    int chunk = p * 256 + tid;
    int orow = chunk >> 3;   // 0..63
    int dseg = chunk & 7;    // 0..7 (8 bf16 along d)
    ushort8_t w;
#pragma unroll
    for (int j = 0; j < 8; ++j) w[j] = f2bf(t[dseg * 8 + j][orow]);
    *reinterpret_cast<ushort8_t*>(Wtc + (size_t)(o0 + orow) * Dd + d0 + dseg * 8) = w;
  }
}

// ---- kernel 3: bucketize tokens by category ----
__global__ void k_bucketize(const int* __restrict__ cid, int* __restrict__ counts,
                            int* __restrict__ bucket, int T) {
  int t = blockIdx.x * blockDim.x + threadIdx.x;
  if (t >= T) return;
  int c = cid[t];
  int p = atomicAdd(&counts[c], 1);
  bucket[c * T + p] = t;
}

// ---- kernel 4: grouped GEMM, 2-phase double-buffered ----
#define BM 128
#define BN 128
#define BK 64

__global__ __launch_bounds__(256) void k_ggemm(
    const unsigned short* __restrict__ xb, const unsigned short* __restrict__ Wt,
    const float* __restrict__ bias, const int* __restrict__ counts,
    const int* __restrict__ bucket, float* __restrict__ out,
    int T, int Dd, int Oo) {
  int c  = blockIdx.z;
  int Mc = counts[c];
  int m0 = blockIdx.y * BM;
  if (m0 >= Mc) return;  // block-uniform exit
  int n0 = blockIdx.x * BN;

  // double-buffered tiles, 64KB total; rows are 128B (64 bf16) wide
  __shared__ __align__(16) unsigned short Al[2][BM * BK];
  __shared__ __align__(16) unsigned short Bl[2][BN * BK];

  const int tid  = threadIdx.x;
  const int lane = tid & 63;
  const int wid  = tid >> 6;
  const int wm   = wid >> 1, wn = wid & 1;  // 2x2 waves, 64x64 each

  const int* buck = bucket + c * T;
  const unsigned short* Wc = Wt + (size_t)c * Oo * Dd;

  // staging plan: per wave, 4 A-loads + 4 B-loads per K-step; load i covers
  // rows [wid*32 + i*8, +8). Linear LDS dest; source seg pre-swizzled
  // (seg = slot' ^ (row&7)) so that swizzled ds_read sees linear data. [rule 21]
  const unsigned short* aSrc[4];
  const unsigned short* bSrc[4];
  int ldsOff[4];  // wave-uniform
#pragma unroll
  for (int i = 0; i < 4; ++i) {
    int row   = wid * 32 + i * 8 + (lane >> 3);
    int slotp = lane & 7;
    int seg   = slotp ^ (row & 7);
    int mr    = m0 + row;
    int tok   = buck[mr < Mc ? mr : Mc - 1];  // clamp; masked at epilogue
    aSrc[i]   = xb + (size_t)tok * Dd + seg * 8;
    bSrc[i]   = Wc + (size_t)(n0 + row) * Dd + seg * 8;
    ldsOff[i] = (wid * 32 + i * 8) * BK;
  }

  const f32x4 fzero = {0.f, 0.f, 0.f, 0.f};
  f32x4 acc[4][4];
#pragma unroll
  for (int i = 0; i < 4; ++i)
#pragma unroll
    for (int j = 0; j < 4; ++j) acc[i][j] = fzero;

  const int KT = Dd / BK;
  int cur = 0;
  // prologue: stage tile 0
#pragma unroll
  for (int i = 0; i < 4; ++i) {
    gload_lds16(aSrc[i], &Al[0][ldsOff[i]]);
    gload_lds16(bSrc[i], &Bl[0][ldsOff[i]]);
  }
  __syncthreads();  // emits s_waitcnt vmcnt(0) lgkmcnt(0) + s_barrier

  for (int kt = 0; kt < KT; ++kt) {
    // issue next tile's async loads (into other buffer) before compute
    if (kt + 1 < KT) {
      int ko = (kt + 1) * BK;
      int nxt = cur ^ 1;
#pragma unroll
      for (int i = 0; i < 4; ++i) {
        gload_lds16(aSrc[i] + ko, &Al[nxt][ldsOff[i]]);
        gload_lds16(bSrc[i] + ko, &Bl[nxt][ldsOff[i]]);
      }
    }
    // compute current tile: 2 K-slabs of 32
#pragma unroll
    for (int kk = 0; kk < 2; ++kk) {
      bf16x8 af[4], bf[4];
#pragma unroll
      for (int mi = 0; mi < 4; ++mi) {
        int row  = wm * 64 + mi * 16 + (lane & 15);
        int slot = (kk * 4 + (lane >> 4)) ^ (row & 7);
        af[mi] = *reinterpret_cast<const bf16x8*>(&Al[cur][row * BK + slot * 8]);
      }
#pragma unroll
      for (int ni = 0; ni < 4; ++ni) {
        int row  = wn * 64 + ni * 16 + (lane & 15);
        int slot = (kk * 4 + (lane >> 4)) ^ (row & 7);
        bf[ni] = *reinterpret_cast<const bf16x8*>(&Bl[cur][row * BK + slot * 8]);
      }
#pragma unroll
      for (int mi = 0; mi < 4; ++mi)
#pragma unroll
        for (int ni = 0; ni < 4; ++ni)
          acc[mi][ni] = __builtin_amdgcn_mfma_f32_16x16x32_bf16(af[mi], bf[ni], acc[mi][ni], 0, 0, 0);
    }
    __syncthreads();  // drains vmcnt(0): next buffer ready; prev reads done
    cur ^= 1;
  }

  // epilogue: D layout col=lane&15, row=(lane>>4)*4+r  [m89-verified]
#pragma unroll
  for (int mi = 0; mi < 4; ++mi) {
    int rb = m0 + wm * 64 + mi * 16 + (lane >> 4) * 4;
#pragma unroll
    for (int r = 0; r < 4; ++r) {
      int mrow = rb + r;
      if (mrow < Mc) {
        int tok = buck[mrow];
        float* orow = out + (size_t)tok * Oo;
#pragma unroll
        for (int ni = 0; ni < 4; ++ni) {
          int col = n0 + wn * 64 + ni * 16 + (lane & 15);
          orow[col] = acc[mi][ni][r] + bias[c * Oo + col];
        }
      }
    }
  }
}

extern "C" void kernel_launch(void* const* d_in, const int* in_sizes, int n_in,
                              void* d_out, int out_size, void* d_ws, size_t ws_size,
                              hipStream_t stream) {
  const float* x    = (const float*)d_in[0];
  const int*   cid  = (const int*)d_in[1];
  const float* W    = (const float*)d_in[2];
  const float* bias = (const float*)d_in[3];
  float* out = (float*)d_out;

  int T = in_sizes[1];            // 4096
  int D = in_sizes[0] / T;        // 1024
  int O = out_size / T;           // 1024
  int C = in_sizes[3] / O;        // 8

  char* ws = (char*)d_ws;
  int* counts = (int*)ws;                                   // C ints
  int* bucket = (int*)(ws + 64);                            // C*T ints
  unsigned short* xb = (unsigned short*)(ws + 64 + (size_t)C * T * 4);   // T*D bf16
  unsigned short* Wt = xb + (size_t)T * D;                  // C*O*D bf16

  hipMemsetAsync(counts, 0, C * sizeof(int), stream);
  k_cvt_x<<<(T * D / 8 + 255) / 256, 256, 0, stream>>>(x, xb, T * D);
  k_transpose_w<<<dim3(O / 64, D / 64, C), 256, 0, stream>>>(W, Wt, D, O);
  k_bucketize<<<(T + 255) / 256, 256, 0, stream>>>(cid, counts, bucket, T);
  k_ggemm<<<dim3(O / BN, (T + BM - 1) / BM, C), 256, 0, stream>>>(
      xb, Wt, bias, counts, bucket, out, T, D, O);
}

// Round 3
// 71.961 us; speedup vs baseline: 1.1240x; 1.0035x over previous
//
#include <hip/hip_runtime.h>

// CategorySpecificLinear: out[t] = x[t] @ W[cid[t]] + bias[cid[t]]
// Pipeline: memset counts -> {cvt x->bf16 + bucketize} -> transpose W->Wt bf16
//           -> grouped MFMA GEMM (depth-3 K-pipeline, counted vmcnt, raw barriers).

typedef __attribute__((ext_vector_type(8))) short bf16x8;
typedef __attribute__((ext_vector_type(4))) float f32x4;
typedef __attribute__((ext_vector_type(8))) unsigned short ushort8_t;

__device__ __forceinline__ unsigned short f2bf(float f) {
  unsigned u = __float_as_uint(f);
  u += 0x7FFFu + ((u >> 16) & 1u);   // round-to-nearest-even
  return (unsigned short)(u >> 16);
}

// async global->LDS, 16B per lane; LDS dest = wave-uniform base + lane*16
__device__ __forceinline__ void gload_lds16(const unsigned short* g, unsigned short* l) {
  __builtin_amdgcn_global_load_lds(
      (const __attribute__((address_space(1))) unsigned int*)g,
      (__attribute__((address_space(3))) unsigned int*)l, 16, 0, 0);
}

// ---- kernel 1: x fp32 -> bf16 (8/thread), fused bucketize in first blocks ----
__global__ void k_cvt_bucket(const float* __restrict__ x, unsigned short* __restrict__ xb,
                             const int* __restrict__ cid, int* __restrict__ counts,
                             int* __restrict__ bucket, int n, int T) {
  int gid = blockIdx.x * blockDim.x + threadIdx.x;
  if (gid < T) {  // bucketize: first T threads
    int c = cid[gid];
    int p = atomicAdd(&counts[c], 1);
    bucket[c * T + p] = gid;
  }
  int i = gid * 8;
  if (i >= n) return;
  float4 a = *reinterpret_cast<const float4*>(x + i);
  float4 b = *reinterpret_cast<const float4*>(x + i + 4);
  ushort8_t o;
  o[0] = f2bf(a.x); o[1] = f2bf(a.y); o[2] = f2bf(a.z); o[3] = f2bf(a.w);
  o[4] = f2bf(b.x); o[5] = f2bf(b.y); o[6] = f2bf(b.z); o[7] = f2bf(b.w);
  *reinterpret_cast<ushort8_t*>(xb + i) = o;
}

// ---- kernel 2: W[c][d][o] fp32 -> Wt[c][o][d] bf16, 64x64 tiles ----
__global__ void k_transpose_w(const float* __restrict__ W, unsigned short* __restrict__ Wt,
                              int Dd, int Oo) {
  __shared__ float t[64][65];
  int c = blockIdx.z, d0 = blockIdx.y * 64, o0 = blockIdx.x * 64;
  const float* Wc = W + (size_t)c * Dd * Oo;
  int tid = threadIdx.x;
#pragma unroll
  for (int p = 0; p < 4; ++p) {
    int chunk = p * 256 + tid;
    int r  = chunk >> 4;    // d row 0..63
    int cb = chunk & 15;    // o col block
    float4 v = *reinterpret_cast<const float4*>(Wc + (size_t)(d0 + r) * Oo + o0 + cb * 4);
    t[r][cb * 4 + 0] = v.x; t[r][cb * 4 + 1] = v.y;
    t[r][cb * 4 + 2] = v.z; t[r][cb * 4 + 3] = v.w;
  }
  __syncthreads();
  unsigned short* Wtc = Wt + (size_t)c * Oo * Dd;
#pragma unroll
  for (int p = 0; p < 2; ++p) {
    int chunk = p * 256 + tid;
    int orow = chunk >> 3;   // 0..63
    int dseg = chunk & 7;    // 0..7
    ushort8_t w;
#pragma unroll
    for (int j = 0; j < 8; ++j) w[j] = f2bf(t[dseg * 8 + j][orow]);
    *reinterpret_cast<ushort8_t*>(Wtc + (size_t)(o0 + orow) * Dd + d0 + dseg * 8) = w;
  }
}

// ---- kernel 3: grouped GEMM, depth-3 K-pipeline with counted vmcnt ----
#define BM 128
#define BN 128
#define BK 64
#define TILE_SH (BM * BK)   // bf16 elements per A (or B) buffer

__global__ __launch_bounds__(256) void k_ggemm(
    const unsigned short* __restrict__ xb, const unsigned short* __restrict__ Wt,
    const float* __restrict__ bias, const int* __restrict__ counts,
    const int* __restrict__ bucket, float* __restrict__ out,
    int T, int Dd, int Oo) {
  int c  = blockIdx.z;
  int Mc = counts[c];
  int m0 = blockIdx.y * BM;
  if (m0 >= Mc) return;  // block-uniform exit
  int n0 = blockIdx.x * BN;

  extern __shared__ __align__(16) unsigned short smem[];  // 96KB dynamic
  unsigned short* Al = smem;                 // 3 x BM*BK
  unsigned short* Bl = smem + 3 * TILE_SH;   // 3 x BN*BK

  const int tid  = threadIdx.x;
  const int lane = tid & 63;
  const int wid  = tid >> 6;
  const int wm   = wid >> 1, wn = wid & 1;  // 2x2 waves, 64x64 each

  const int* buck = bucket + c * T;
  const unsigned short* Wc = Wt + (size_t)c * Oo * Dd;

  // staging: per wave 4 A + 4 B gloads per tile; load i covers rows [wid*32+i*8, +8).
  // Linear LDS dest; global source seg pre-swizzled (seg = slot' ^ (row&7)) so the
  // swizzled ds_read below sees the right data. [rule 21; verified rounds 1-2]
  const unsigned short* aSrc[4];
  const unsigned short* bSrc[4];
  int ldsOff[4];  // wave-uniform
#pragma unroll
  for (int i = 0; i < 4; ++i) {
    int row   = wid * 32 + i * 8 + (lane >> 3);
    int slotp = lane & 7;
    int seg   = slotp ^ (row & 7);
    int mr    = m0 + row;
    int tok   = buck[mr < Mc ? mr : Mc - 1];  // clamp; masked at epilogue
    aSrc[i]   = xb + (size_t)tok * Dd + seg * 8;
    bSrc[i]   = Wc + (size_t)(n0 + row) * Dd + seg * 8;
    ldsOff[i] = (wid * 32 + i * 8) * BK;
  }

  const f32x4 fzero = {0.f, 0.f, 0.f, 0.f};
  f32x4 acc[4][4];
#pragma unroll
  for (int i = 0; i < 4; ++i)
#pragma unroll
    for (int j = 0; j < 4; ++j) acc[i][j] = fzero;

  const int KT = Dd / BK;  // 16

  // prologue: issue tiles 0 and 1 into buffers 0,1 (8 gloads each per wave)
#pragma unroll
  for (int i = 0; i < 4; ++i) {
    gload_lds16(aSrc[i], Al + 0 * TILE_SH + ldsOff[i]);
    gload_lds16(bSrc[i], Bl + 0 * TILE_SH + ldsOff[i]);
  }
#pragma unroll
  for (int i = 0; i < 4; ++i) {
    gload_lds16(aSrc[i] + BK, Al + 1 * TILE_SH + ldsOff[i]);
    gload_lds16(bSrc[i] + BK, Bl + 1 * TILE_SH + ldsOff[i]);
  }

  int cur = 0;
  for (int kt = 0; kt < KT; ++kt) {
    // seam: my prev ds_reads done (free), tile kt's 8 loads landed (8 newer may fly)
    asm volatile("s_waitcnt lgkmcnt(0)" ::: "memory");
    if (kt < KT - 1) {
      asm volatile("s_waitcnt vmcnt(8)" ::: "memory");
    } else {
      asm volatile("s_waitcnt vmcnt(0)" ::: "memory");
    }
    __builtin_amdgcn_sched_barrier(0);
    __builtin_amdgcn_s_barrier();
    __builtin_amdgcn_sched_barrier(0);

    // issue tile kt+2 into buffer (cur+2)%3 — its readers finished before the barrier
    if (kt + 2 < KT) {
      int nb = cur + 2; if (nb >= 3) nb -= 3;
      int ko = (kt + 2) * BK;
      unsigned short* An = Al + nb * TILE_SH;
      unsigned short* Bn = Bl + nb * TILE_SH;
#pragma unroll
      for (int i = 0; i < 4; ++i) {
        gload_lds16(aSrc[i] + ko, An + ldsOff[i]);
        gload_lds16(bSrc[i] + ko, Bn + ldsOff[i]);
      }
    }

    const unsigned short* Ac = Al + cur * TILE_SH;
    const unsigned short* Bc = Bl + cur * TILE_SH;
#pragma unroll
    for (int kk = 0; kk < 2; ++kk) {
      bf16x8 af[4], bf[4];
#pragma unroll
      for (int mi = 0; mi < 4; ++mi) {
        int row  = wm * 64 + mi * 16 + (lane & 15);
        int slot = (kk * 4 + (lane >> 4)) ^ (row & 7);
        af[mi] = *reinterpret_cast<const bf16x8*>(&Ac[row * BK + slot * 8]);
      }
#pragma unroll
      for (int ni = 0; ni < 4; ++ni) {
        int row  = wn * 64 + ni * 16 + (lane & 15);
        int slot = (kk * 4 + (lane >> 4)) ^ (row & 7);
        bf[ni] = *reinterpret_cast<const bf16x8*>(&Bc[row * BK + slot * 8]);
      }
#pragma unroll
      for (int mi = 0; mi < 4; ++mi)
#pragma unroll
        for (int ni = 0; ni < 4; ++ni)
          acc[mi][ni] = __builtin_amdgcn_mfma_f32_16x16x32_bf16(af[mi], bf[ni], acc[mi][ni], 0, 0, 0);
    }
    cur = (cur + 1 == 3) ? 0 : cur + 1;
  }

  // epilogue: D layout col=lane&15, row=(lane>>4)*4+r  [m89-verified]
#pragma unroll
  for (int mi = 0; mi < 4; ++mi) {
    int rb = m0 + wm * 64 + mi * 16 + (lane >> 4) * 4;
#pragma unroll
    for (int r = 0; r < 4; ++r) {
      int mrow = rb + r;
      if (mrow < Mc) {
        int tok = buck[mrow];
        float* orow = out + (size_t)tok * Oo;
#pragma unroll
        for (int ni = 0; ni < 4; ++ni) {
          int col = n0 + wn * 64 + ni * 16 + (lane & 15);
          orow[col] = acc[mi][ni][r] + bias[c * Oo + col];
        }
      }
    }
  }
}

extern "C" void kernel_launch(void* const* d_in, const int* in_sizes, int n_in,
                              void* d_out, int out_size, void* d_ws, size_t ws_size,
                              hipStream_t stream) {
  const float* x    = (const float*)d_in[0];
  const int*   cid  = (const int*)d_in[1];
  const float* W    = (const float*)d_in[2];
  const float* bias = (const float*)d_in[3];
  float* out = (float*)d_out;

  int T = in_sizes[1];            // 4096
  int D = in_sizes[0] / T;        // 1024
  int O = out_size / T;           // 1024
  int C = in_sizes[3] / O;        // 8

  char* ws = (char*)d_ws;
  int* counts = (int*)ws;                                   // C ints
  int* bucket = (int*)(ws + 64);                            // C*T ints
  unsigned short* xb = (unsigned short*)(ws + 64 + (size_t)C * T * 4);   // T*D bf16
  unsigned short* Wt = xb + (size_t)T * D;                  // C*O*D bf16

  hipMemsetAsync(counts, 0, C * sizeof(int), stream);
  k_cvt_bucket<<<(T * D / 8 + 255) / 256, 256, 0, stream>>>(x, xb, cid, counts, bucket, T * D, T);
  k_transpose_w<<<dim3(O / 64, D / 64, C), 256, 0, stream>>>(W, Wt, D, O);
  size_t ldsBytes = (size_t)6 * TILE_SH * sizeof(unsigned short);  // 96KB
  k_ggemm<<<dim3(O / BN, (T + BM - 1) / BM, C), 256, ldsBytes, stream>>>(
      xb, Wt, bias, counts, bucket, out, T, D, O);
}

// Round 4
// 63.530 us; speedup vs baseline: 1.2732x; 1.1327x over previous
//
#include <hip/hip_runtime.h>

// CategorySpecificLinear: out[t] = x[t] @ W[cid[t]] + bias[cid[t]]
// Pipeline: memset counts -> {cvt x->bf16 + bucketize} -> transpose W->Wt bf16
//           -> grouped MFMA GEMM (depth-3 counted-vmcnt pipeline, cat->XCD L2 partition).

typedef __attribute__((ext_vector_type(8))) short bf16x8;
typedef __attribute__((ext_vector_type(4))) float f32x4;
typedef __attribute__((ext_vector_type(8))) unsigned short ushort8_t;

__device__ __forceinline__ unsigned short f2bf(float f) {
  unsigned u = __float_as_uint(f);
  u += 0x7FFFu + ((u >> 16) & 1u);   // round-to-nearest-even
  return (unsigned short)(u >> 16);
}

// async global->LDS, 16B per lane; LDS dest = wave-uniform base + lane*16
__device__ __forceinline__ void gload_lds16(const unsigned short* g, unsigned short* l) {
  __builtin_amdgcn_global_load_lds(
      (const __attribute__((address_space(1))) unsigned int*)g,
      (__attribute__((address_space(3))) unsigned int*)l, 16, 0, 0);
}

// ---- kernel 1: x fp32 -> bf16 (8/thread), fused bucketize ---- (unchanged from R3)
__global__ void k_cvt_bucket(const float* __restrict__ x, unsigned short* __restrict__ xb,
                             const int* __restrict__ cid, int* __restrict__ counts,
                             int* __restrict__ bucket, int n, int T) {
  int gid = blockIdx.x * blockDim.x + threadIdx.x;
  if (gid < T) {
    int c = cid[gid];
    int p = atomicAdd(&counts[c], 1);
    bucket[c * T + p] = gid;
  }
  int i = gid * 8;
  if (i >= n) return;
  float4 a = *reinterpret_cast<const float4*>(x + i);
  float4 b = *reinterpret_cast<const float4*>(x + i + 4);
  ushort8_t o;
  o[0] = f2bf(a.x); o[1] = f2bf(a.y); o[2] = f2bf(a.z); o[3] = f2bf(a.w);
  o[4] = f2bf(b.x); o[5] = f2bf(b.y); o[6] = f2bf(b.z); o[7] = f2bf(b.w);
  *reinterpret_cast<ushort8_t*>(xb + i) = o;
}

// ---- kernel 2: W[c][d][o] fp32 -> Wt[c][o][d] bf16 ---- (unchanged from R3)
__global__ void k_transpose_w(const float* __restrict__ W, unsigned short* __restrict__ Wt,
                              int Dd, int Oo) {
  __shared__ float t[64][65];
  int c = blockIdx.z, d0 = blockIdx.y * 64, o0 = blockIdx.x * 64;
  const float* Wc = W + (size_t)c * Dd * Oo;
  int tid = threadIdx.x;
#pragma unroll
  for (int p = 0; p < 4; ++p) {
    int chunk = p * 256 + tid;
    int r  = chunk >> 4;
    int cb = chunk & 15;
    float4 v = *reinterpret_cast<const float4*>(Wc + (size_t)(d0 + r) * Oo + o0 + cb * 4);
    t[r][cb * 4 + 0] = v.x; t[r][cb * 4 + 1] = v.y;
    t[r][cb * 4 + 2] = v.z; t[r][cb * 4 + 3] = v.w;
  }
  __syncthreads();
  unsigned short* Wtc = Wt + (size_t)c * Oo * Dd;
#pragma unroll
  for (int p = 0; p < 2; ++p) {
    int chunk = p * 256 + tid;
    int orow = chunk >> 3;
    int dseg = chunk & 7;
    ushort8_t w;
#pragma unroll
    for (int j = 0; j < 8; ++j) w[j] = f2bf(t[dseg * 8 + j][orow]);
    *reinterpret_cast<ushort8_t*>(Wtc + (size_t)(o0 + orow) * Dd + d0 + dseg * 8) = w;
  }
}

// ---- kernel 3: grouped GEMM ----
// BM=64 x BN=128, BK=64, depth-3 pipeline. Grid (C, N, M): blockIdx.x = category
// => linear wg id % 8 == c => all blocks of category c on XCD c => Wt_c (2MB) +
// x_c (~1MB) are L2-resident per XCD. Staging rides L2 not L3.
#define BM 64
#define BN 128
#define BK 64
#define TILE_A (BM * BK)   // 4096 elems = 8KB
#define TILE_B (BN * BK)   // 8192 elems = 16KB

__global__ __launch_bounds__(256) void k_ggemm(
    const unsigned short* __restrict__ xb, const unsigned short* __restrict__ Wt,
    const float* __restrict__ bias, const int* __restrict__ counts,
    const int* __restrict__ bucket, float* __restrict__ out,
    int T, int Dd, int Oo) {
  int c  = blockIdx.x;
  int Mc = counts[c];
  int m0 = blockIdx.z * BM;
  if (m0 >= Mc) return;  // block-uniform exit
  int n0 = blockIdx.y * BN;

  extern __shared__ __align__(16) unsigned short smem[];  // 72KB dynamic
  unsigned short* Al = smem;                 // 3 x TILE_A
  unsigned short* Bl = smem + 3 * TILE_A;    // 3 x TILE_B

  const int tid  = threadIdx.x;
  const int lane = tid & 63;
  const int wid  = tid >> 6;
  const int wm   = wid >> 1, wn = wid & 1;  // 2x2 waves, each 32x64 of C

  const int* buck = bucket + c * T;
  const unsigned short* Wc = Wt + (size_t)c * Oo * Dd;

  // staging: per wave 2 A-gloads (rows wid*16+i*8..+8) + 4 B-gloads (rows wid*32+i*8..+8).
  // Linear LDS dest; global source seg pre-swizzled (seg = (lane&7) ^ (row&7)) so the
  // swizzled ds_read below reads linear k. [rule 21; correctness-proven R1-R3]
  const unsigned short* aSrc[2];
  const unsigned short* bSrc[4];
  int aOff[2], bOff[4];  // wave-uniform LDS element offsets
#pragma unroll
  for (int i = 0; i < 2; ++i) {
    int row = wid * 16 + i * 8 + (lane >> 3);
    int seg = (lane & 7) ^ (row & 7);
    int mr  = m0 + row;
    int tok = buck[mr < Mc ? mr : Mc - 1];  // clamp; masked at epilogue
    aSrc[i] = xb + (size_t)tok * Dd + seg * 8;
    aOff[i] = (wid * 16 + i * 8) * BK;
  }
#pragma unroll
  for (int i = 0; i < 4; ++i) {
    int row = wid * 32 + i * 8 + (lane >> 3);
    int seg = (lane & 7) ^ (row & 7);
    bSrc[i] = Wc + (size_t)(n0 + row) * Dd + seg * 8;
    bOff[i] = (wid * 32 + i * 8) * BK;
  }

  const f32x4 fzero = {0.f, 0.f, 0.f, 0.f};
  f32x4 acc[2][4];
#pragma unroll
  for (int i = 0; i < 2; ++i)
#pragma unroll
    for (int j = 0; j < 4; ++j) acc[i][j] = fzero;

  const int KT = Dd / BK;  // 16

  // prologue: issue tiles 0 and 1 (6 gloads each per wave)
#pragma unroll
  for (int t8 = 0; t8 < 2; ++t8) {
    unsigned short* Ab = Al + t8 * TILE_A;
    unsigned short* Bb = Bl + t8 * TILE_B;
    int ko = t8 * BK;
#pragma unroll
    for (int i = 0; i < 2; ++i) gload_lds16(aSrc[i] + ko, Ab + aOff[i]);
#pragma unroll
    for (int i = 0; i < 4; ++i) gload_lds16(bSrc[i] + ko, Bb + bOff[i]);
  }

  int cur = 0;
  for (int kt = 0; kt < KT; ++kt) {
    // my prev ds_reads drained (so buffer cur+2 is safe for ALL waves after barrier);
    // tile kt's 6 loads landed (6 newer may stay in flight)
    asm volatile("s_waitcnt lgkmcnt(0)" ::: "memory");
    if (kt < KT - 1) {
      asm volatile("s_waitcnt vmcnt(6)" ::: "memory");
    } else {
      asm volatile("s_waitcnt vmcnt(0)" ::: "memory");
    }
    __builtin_amdgcn_sched_barrier(0);
    __builtin_amdgcn_s_barrier();
    __builtin_amdgcn_sched_barrier(0);

    if (kt + 2 < KT) {
      int nb = cur + 2; if (nb >= 3) nb -= 3;
      int ko = (kt + 2) * BK;
      unsigned short* An = Al + nb * TILE_A;
      unsigned short* Bn = Bl + nb * TILE_B;
#pragma unroll
      for (int i = 0; i < 2; ++i) gload_lds16(aSrc[i] + ko, An + aOff[i]);
#pragma unroll
      for (int i = 0; i < 4; ++i) gload_lds16(bSrc[i] + ko, Bn + bOff[i]);
    }

    const unsigned short* Ac = Al + cur * TILE_A;
    const unsigned short* Bc = Bl + cur * TILE_B;
#pragma unroll
    for (int kk = 0; kk < 2; ++kk) {
      bf16x8 af[2], bf[4];
#pragma unroll
      for (int mi = 0; mi < 2; ++mi) {
        int row  = wm * 32 + mi * 16 + (lane & 15);
        int slot = (kk * 4 + (lane >> 4)) ^ (row & 7);
        af[mi] = *reinterpret_cast<const bf16x8*>(&Ac[row * BK + slot * 8]);
      }
#pragma unroll
      for (int ni = 0; ni < 4; ++ni) {
        int row  = wn * 64 + ni * 16 + (lane & 15);
        int slot = (kk * 4 + (lane >> 4)) ^ (row & 7);
        bf[ni] = *reinterpret_cast<const bf16x8*>(&Bc[row * BK + slot * 8]);
      }
      __builtin_amdgcn_s_setprio(1);
#pragma unroll
      for (int mi = 0; mi < 2; ++mi)
#pragma unroll
        for (int ni = 0; ni < 4; ++ni)
          acc[mi][ni] = __builtin_amdgcn_mfma_f32_16x16x32_bf16(af[mi], bf[ni], acc[mi][ni], 0, 0, 0);
      __builtin_amdgcn_s_setprio(0);
    }
    cur = (cur + 1 == 3) ? 0 : cur + 1;
  }

  // epilogue: D layout col=lane&15, row=(lane>>4)*4+r  [m89-verified]
#pragma unroll
  for (int mi = 0; mi < 2; ++mi) {
    int rb = m0 + wm * 32 + mi * 16 + (lane >> 4) * 4;
#pragma unroll
    for (int r = 0; r < 4; ++r) {
      int mrow = rb + r;
      if (mrow < Mc) {
        int tok = buck[mrow];
        float* orow = out + (size_t)tok * Oo;
#pragma unroll
        for (int ni = 0; ni < 4; ++ni) {
          int col = n0 + wn * 64 + ni * 16 + (lane & 15);
          orow[col] = acc[mi][ni][r] + bias[c * Oo + col];
        }
      }
    }
  }
}

extern "C" void kernel_launch(void* const* d_in, const int* in_sizes, int n_in,
                              void* d_out, int out_size, void* d_ws, size_t ws_size,
                              hipStream_t stream) {
  const float* x    = (const float*)d_in[0];
  const int*   cid  = (const int*)d_in[1];
  const float* W    = (const float*)d_in[2];
  const float* bias = (const float*)d_in[3];
  float* out = (float*)d_out;

  int T = in_sizes[1];            // 4096
  int D = in_sizes[0] / T;        // 1024
  int O = out_size / T;           // 1024
  int C = in_sizes[3] / O;        // 8

  char* ws = (char*)d_ws;
  int* counts = (int*)ws;                                   // C ints
  int* bucket = (int*)(ws + 64);                            // C*T ints
  unsigned short* xb = (unsigned short*)(ws + 64 + (size_t)C * T * 4);   // T*D bf16
  unsigned short* Wt = xb + (size_t)T * D;                  // C*O*D bf16

  hipMemsetAsync(counts, 0, C * sizeof(int), stream);
  k_cvt_bucket<<<(T * D / 8 + 255) / 256, 256, 0, stream>>>(x, xb, cid, counts, bucket, T * D, T);
  k_transpose_w<<<dim3(O / 64, D / 64, C), 256, 0, stream>>>(W, Wt, D, O);
  size_t ldsBytes = (size_t)3 * (TILE_A + TILE_B) * sizeof(unsigned short);  // 72KB
  k_ggemm<<<dim3(C, O / BN, (T + BM - 1) / BM), 256, ldsBytes, stream>>>(
      xb, Wt, bias, counts, bucket, out, T, D, O);
}